// Round 6
// baseline (185.539 us; speedup 1.0000x reference)
//
#include <hip/hip_runtime.h>
#include <cstdint>
#include <cstddef>

#define B_   2
#define N_   2048
#define D_   1024
#define H_   16
#define HD_  64
// SCALE * log2(e), folded into Q in the GEMM epilogue
#define QSCALE_ 0.18033688011112042f

typedef unsigned short u16;
typedef unsigned int   u32;
typedef __attribute__((ext_vector_type(8))) short short8;   // bf16 MFMA A/B frag
typedef __attribute__((ext_vector_type(4))) float f32x4;    // MFMA C/D frag (16x16)
typedef __attribute__((ext_vector_type(16))) float f32x16;  // MFMA C/D frag (32x32)
typedef __attribute__((ext_vector_type(4))) float fl4;
typedef __attribute__((ext_vector_type(4))) unsigned short us4;
typedef __attribute__((ext_vector_type(4))) unsigned int u32x4;

#if __has_builtin(__builtin_amdgcn_exp2f)
#define EXP2F(x) __builtin_amdgcn_exp2f(x)   // raw v_exp_f32, no OCML denorm guards
#else
#define EXP2F(x) exp2f(x)
#endif

__device__ __forceinline__ u16 f2bf(float f) {
  u32 u = __builtin_bit_cast(u32, f);
  u += 0x7fffu + ((u >> 16) & 1u);   // RNE; inputs finite
  return (u16)(u >> 16);
}

// pack two f32 -> one u32 of 2 bf16 (RNE), elem0 in low half
__device__ __forceinline__ u32 cvtpk(float lo, float hi) {
  u32 r;
  asm("v_cvt_pk_bf16_f32 %0, %1, %2" : "=v"(r) : "v"(lo), "v"(hi));
  return r;
}

// v_permlane32_swap_b32 a, b: a[32:63] <-> b[0:31]
__device__ __forceinline__ void plswap(u32& a, u32& b) {
  asm volatile("v_permlane32_swap_b32 %0, %1" : "+v"(a), "+v"(b));
}

__device__ __forceinline__ void gload16(const void* g, void* l) {
  typedef __attribute__((address_space(1))) unsigned int gu32;
  typedef __attribute__((address_space(3))) unsigned int lu32;
  __builtin_amdgcn_global_load_lds((gu32*)g, (lu32*)l, 16, 0, 0);
}

// ---------------- fp32 -> bf16 conversion of x1, x2, W ----------------
// Convert-once matters beyond FLOPs: bf16 panels keep the qkv staging working
// set L2-resident (R4 evidence: f32 direct reads -> FETCH 69->191MB, 1.75x slower).
__global__ void convert_kernel(const fl4* __restrict__ x1, const fl4* __restrict__ x2,
                               const fl4* __restrict__ w,
                               us4* __restrict__ o1, us4* __restrict__ o2,
                               us4* __restrict__ ow) {
  const int NX = (B_ * N_ * D_) / 4;   // 1048576
  const int NW = (3 * D_ * D_) / 4;    // 786432
  int stride = gridDim.x * blockDim.x;
  for (int i = blockIdx.x * blockDim.x + threadIdx.x; i < NX; i += stride) {
    fl4 a = x1[i];
    us4 r; r.x = f2bf(a.x); r.y = f2bf(a.y); r.z = f2bf(a.z); r.w = f2bf(a.w);
    o1[i] = r;
    fl4 b = x2[i];
    us4 s; s.x = f2bf(b.x); s.y = f2bf(b.y); s.z = f2bf(b.z); s.w = f2bf(b.w);
    o2[i] = s;
    if (i < NW) {
      fl4 c = w[i];
      us4 t; t.x = f2bf(c.x); t.y = f2bf(c.y); t.z = f2bf(c.z); t.w = f2bf(c.w);
      ow[i] = t;
    }
  }
}

// ---------------- fused QKV GEMM v4: counted-vmcnt 3-slot ring (T4) + XCD swizzle (T1) --------
// R5 post-mortem: __syncthreads' vmcnt(0) drain pays full load latency every K-step (null vs
// 2-barrier).  v4 keeps the exact R5 tile/frag/epilogue but replaces the sync with:
//   3-slot LDS ring (3x16KB=48KB), stage unit u+2 while computing u, and a raw
//   `s_waitcnt vmcnt(4)` + s_barrier at iteration end: slot u+1 is provably resident (FIFO
//   vmcnt), slot u+2's 4 loads stay IN FLIGHT ACROSS the barrier -> ~2 compute phases of
//   latency cover.  Slot aliasing: read u%3 / resident (u+1)%3 / write (u+2)%3, disjoint;
//   a slot is overwritten only after the barrier ending its reading iteration.
// T1: 768 blocks (768%8==0), swz=(wg&7)*96+(wg>>3): each XCD chunk = 3 complete (z,e) panel
// groups -> each 256KB W-panel fetched once per XCD-L2, reused 32x.
__global__ __launch_bounds__(256) void qkv_gemm(
    const u16* __restrict__ x1b, const u16* __restrict__ x2b,
    const u16* __restrict__ wb, const float* __restrict__ bias,
    u16* __restrict__ Qb, u16* __restrict__ Kb, u16* __restrict__ Vtb) {
  const int wg  = blockIdx.x;
  const int swz = (wg & 7) * 96 + (wg >> 3);   // XCD-contiguous chunks
  const int z   = swz >> 8;                    // 0..2
  const int e0  = ((swz >> 5) & 7) * 128;      // 0..7  *128
  const int m0  = (swz & 31) * 128;            // 0..31 *128

  const u16* X = (z == 0) ? x1b : x2b;
  const u16* W = wb + (size_t)z * D_ * D_;
  const float* bz = bias + z * D_;
  const int tid = threadIdx.x;
  const int lane = tid & 63;
  const int w = tid >> 6;
  const int wr = w >> 1, wc = w & 1;
  const int col = lane & 15, quad = lane >> 4;

  // ring: slot = 8192 u16 (A[128][32] at +0, B[128][32] at +4096)
  __shared__ __align__(16) u16 lds[3 * 8192];

  f32x4 acc[4][4] = {};

  // staging: thread covers dest granules tid and tid+256 of each 8KB half
  // (rows tid>>2 and 64+tid>>2, 16B granule (tid&3) within the 64B row)
  const int srow = tid >> 2;
  const int sseg = tid & 3;
  const u16* srcA = X + (size_t)(m0 + srow) * D_ + sseg * 8;
  const u16* srcB = W + (size_t)(e0 + srow) * D_ + sseg * 8;
  u16* dA = &lds[w * 512];          // wave-uniform dest bases (+ slot offset)
  u16* dB = &lds[4096 + w * 512];

#define STAGE(uu, soff)                                   \
  do {                                                    \
    const int kk0 = (uu) * 32;                            \
    gload16(srcA + kk0,           dA + (soff));           \
    gload16(srcA + 64 * D_ + kk0, dA + (soff) + 2048);    \
    gload16(srcB + kk0,           dB + (soff));           \
    gload16(srcB + 64 * D_ + kk0, dB + (soff) + 2048);    \
  } while (0)

#define COMPUTE(roff)                                                        \
  do {                                                                       \
    const u16* Ar = &lds[(roff)];                                            \
    const u16* Br = &lds[(roff) + 4096];                                     \
    short8 a[4], b[4];                                                       \
    _Pragma("unroll")                                                        \
    for (int i = 0; i < 4; ++i)                                              \
      a[i] = *(const short8*)&Ar[(wr * 64 + i * 16 + col) * 32 + quad * 8];  \
    _Pragma("unroll")                                                        \
    for (int j = 0; j < 4; ++j)                                              \
      b[j] = *(const short8*)&Br[(wc * 64 + j * 16 + col) * 32 + quad * 8];  \
    __builtin_amdgcn_s_setprio(1);                                           \
    _Pragma("unroll")                                                        \
    for (int i = 0; i < 4; ++i)                                              \
      _Pragma("unroll")                                                      \
      for (int j = 0; j < 4; ++j)                                            \
        acc[i][j] = __builtin_amdgcn_mfma_f32_16x16x32_bf16(a[i], b[j],      \
                                                            acc[i][j], 0, 0, 0); \
    __builtin_amdgcn_s_setprio(0);                                           \
  } while (0)

  // prologue: units 0,1 -> slots 0,1; wait unit 0 resident (unit 1 may be in flight)
  STAGE(0, 0);
  STAGE(1, 8192);
  asm volatile("s_waitcnt vmcnt(4)" ::: "memory");
  __builtin_amdgcn_s_barrier();
  asm volatile("" ::: "memory");

  int r_off = 0, s_off = 16384;
  for (int u = 0; u < 30; ++u) {
    STAGE(u + 2, s_off);
    COMPUTE(r_off);
    // counted drain: slot u+1 resident, slot u+2 (4 loads) stays in flight
    asm volatile("s_waitcnt vmcnt(4)" ::: "memory");
    __builtin_amdgcn_s_barrier();
    asm volatile("" ::: "memory");
    r_off = (r_off == 16384) ? 0 : r_off + 8192;
    s_off = (s_off == 16384) ? 0 : s_off + 8192;
  }
  // tail: drain everything once, then two stage-free iterations (no writes -> no barriers)
  asm volatile("s_waitcnt vmcnt(0)" ::: "memory");
  __builtin_amdgcn_s_barrier();
  asm volatile("" ::: "memory");
  COMPUTE(r_off);
  r_off = (r_off == 16384) ? 0 : r_off + 8192;
  COMPUTE(r_off);
#undef STAGE
#undef COMPUTE

#pragma unroll
  for (int j = 0; j < 4; ++j) {
    int eg = e0 + wc * 64 + j * 16 + col;
    float bj = bz[eg];
    int h = eg >> 6, d = eg & 63;
#pragma unroll
    for (int i = 0; i < 4; ++i) {
#pragma unroll
      for (int r = 0; r < 4; ++r) {
        int m = m0 + wr * 64 + i * 16 + quad * 4 + r;
        int bb = m >> 11, n = m & (N_ - 1);
        float v = acc[i][j][r] + bj;
        if (z == 0) v *= QSCALE_;
        u16 o = f2bf(v);
        if (z == 0)      Qb [(((size_t)bb * H_ + h) * N_ + n) * HD_ + d] = o;
        else if (z == 1) Kb [(((size_t)bb * H_ + h) * N_ + n) * HD_ + d] = o;
        else             Vtb[(((size_t)bb * H_ + h) * HD_ + d) * N_ + n] = o;
      }
    }
  }
}

// ---------------- fused attention v5: 32x32 MFMA, swapped QK^T, in-register softmax ----------------
// block = 4 waves x 32 q-rows = 128 q; BK = 64 keys/tile; grid 16 x 32 = 512 (2 blocks/CU).
// S^T = mfma(K, Q): col=lane&31 = q (ONE q per lane), row = key = (reg&3)+8*(reg>>2)+4*(lane>>5).
// Softmax denominator is a per-lane scalar (+1 shfl at epilogue). P -> PV A-frags built fully
// in-register: cvt_pk_bf16 pairs + permlane32_swap (T12).  No P LDS, no lgkm serialization.
// K/V tiles: double-buffered XOR-swizzled [64][64], one barrier/tile, reg-staged prefetch.
__global__ __launch_bounds__(256, 2) void attn_kernel(
    const u16* __restrict__ Qb, const u16* __restrict__ Kb,
    const u16* __restrict__ Vtb, float* __restrict__ out) {
  const int bh = blockIdx.y;                 // 0..31
  const int bb = bh >> 4, h = bh & 15;
  const int q0 = blockIdx.x * 128;
  const int tid = threadIdx.x;
  const int lane = tid & 63;
  const int w = tid >> 6;
  const int l31 = lane & 31, hf = lane >> 5, r7 = lane & 7;

  const u16* __restrict__ Q  = Qb  + ((size_t)bh << 17);   // bh * N*HD
  const u16* __restrict__ K  = Kb  + ((size_t)bh << 17);
  const u16* __restrict__ Vt = Vtb + ((size_t)bh << 17);

  __shared__ __align__(16) u16 Ks[2][64 * 64];   // [buf][key][d]  swizzled
  __shared__ __align__(16) u16 Vs[2][64 * 64];   // [buf][d][key]  swizzled
  __shared__ float Ls[4][32];                    // per-wave 1/denominator

  // Q B-frags: col = q = l31, chunk c covers d = c*16 + hf*8 + j
  const u16* Qr = Q + (size_t)(q0 + w * 32 + l31) * HD_;
  short8 qf[4];
#pragma unroll
  for (int c = 0; c < 4; ++c)
    qf[c] = *(const short8*)&Qr[c * 16 + hf * 8];

  // cooperative staging: 256 threads x 16B granules; swizzled write slots
  const int srow = tid >> 3;              // 0..31
  const int sg   = tid & 7;
  const int lw0 = srow * 64 + ((sg ^ (srow & 7)) * 8);
  const int lw1 = lw0 + 2048;                            // row+32: (row&7) unchanged
  const u16* gK = K + tid * 8;                           // + k0*64 (+2048 rows 32..63)
  const u16* gV = Vt + srow * N_ + sg * 8;               // + k0   (+32*N_ d 32..63)

  f32x16 accO[2] = {};
  float lsum = 0.f;

  // prologue: tile 0 -> regs -> buf 0
  short8 kA = *(const short8*)(gK);
  short8 kB = *(const short8*)(gK + 2048);
  short8 vA = *(const short8*)(gV);
  short8 vB = *(const short8*)(gV + 32 * N_);
  *(short8*)&Ks[0][lw0] = kA;
  *(short8*)&Ks[0][lw1] = kB;
  *(short8*)&Vs[0][lw0] = vA;
  *(short8*)&Vs[0][lw1] = vB;

  for (int t = 0; t < N_ / 64; ++t) {
    __syncthreads();                     // buf[cur] writes visible to all waves
    const int cur = t & 1;
    if (t < N_ / 64 - 1) {               // prefetch next tile; consumed only by tail write
      const int k0n = (t + 1) * 64;
      kA = *(const short8*)(gK + k0n * 64);
      kB = *(const short8*)(gK + k0n * 64 + 2048);
      vA = *(const short8*)(gV + k0n);
      vB = *(const short8*)(gV + k0n + 32 * N_);
    }
    const u16* Kc = Ks[cur];
    const u16* Vc = Vs[cur];

    // S^T = K Q^T: A = K[key][d] (row=key=l31 per 32-block), B = Q (col=q)
    f32x16 sT[2] = {};
    __builtin_amdgcn_s_setprio(1);
#pragma unroll
    for (int kb = 0; kb < 2; ++kb) {
      const int rb = (kb * 32 + l31) * 64;
#pragma unroll
      for (int c = 0; c < 4; ++c) {
        short8 kf = *(const short8*)&Kc[rb + (((c * 2 + hf) ^ r7) * 8)];
        sT[kb] = __builtin_amdgcn_mfma_f32_32x32x16_bf16(kf, qf[c], sT[kb], 0, 0, 0);
      }
    }
    __builtin_amdgcn_s_setprio(0);

    // exp2 in-register (arg pre-scaled by SCALE*log2e; no max needed), scalar denom
#pragma unroll
    for (int kb = 0; kb < 2; ++kb)
#pragma unroll
      for (int i = 0; i < 16; ++i) {
        float e = EXP2F(sT[kb][i]);
        lsum += e;
        sT[kb][i] = e;
      }

    // build PV A-frags fully in-register: chunk kc = keys kc*16..+15 of the tile.
    short8 pf[4];
#pragma unroll
    for (int kc = 0; kc < 4; ++kc) {
      const int kb = kc >> 1, o = (kc & 1) * 8;
      u32 X = cvtpk(sT[kb][o + 0], sT[kb][o + 1]);
      u32 Y = cvtpk(sT[kb][o + 4], sT[kb][o + 5]);
      plswap(X, Y);
      u32 Z = cvtpk(sT[kb][o + 2], sT[kb][o + 3]);
      u32 W = cvtpk(sT[kb][o + 6], sT[kb][o + 7]);
      plswap(Z, W);
      u32x4 pw = {X, Z, Y, W};
      pf[kc] = __builtin_bit_cast(short8, pw);
    }

    // O += P V : A = P (row=q), B = V^T[d][key] (col=d), k=key
    __builtin_amdgcn_s_setprio(1);
#pragma unroll
    for (int db = 0; db < 2; ++db) {
      const int rb = (db * 32 + l31) * 64;
#pragma unroll
      for (int kc = 0; kc < 4; ++kc) {
        short8 vf = *(const short8*)&Vc[rb + (((kc * 2 + hf) ^ r7) * 8)];
        accO[db] = __builtin_amdgcn_mfma_f32_32x32x16_bf16(pf[kc], vf, accO[db], 0, 0, 0);
      }
    }
    __builtin_amdgcn_s_setprio(0);

    // tail: commit prefetched tile into the other buffer (vmcnt lands here, hidden)
    if (t < N_ / 64 - 1) {
      u16* Kn = (u16*)Ks[cur ^ 1];
      u16* Vn = (u16*)Vs[cur ^ 1];
      *(short8*)&Kn[lw0] = kA;
      *(short8*)&Kn[lw1] = kB;
      *(short8*)&Vn[lw0] = vA;
      *(short8*)&Vn[lw1] = vB;
    }
  }

  // denominator: lane pair (l, l^32) holds complementary key halves for q = l31
  lsum += __shfl_xor(lsum, 32);
  if (hf == 0) Ls[w][l31] = 1.0f / lsum;
  __syncthreads();

  float rinv[16];
#pragma unroll
  for (int r = 0; r < 16; ++r)
    rinv[r] = Ls[w][(r & 3) + 8 * (r >> 2) + 4 * hf];

#pragma unroll
  for (int db = 0; db < 2; ++db)
#pragma unroll
    for (int r = 0; r < 16; ++r) {
      int n = q0 + w * 32 + (r & 3) + 8 * (r >> 2) + 4 * hf;
      int e = h * HD_ + db * 32 + l31;
      out[((size_t)bb * N_ + n) * D_ + e] = accO[db][r] * rinv[r];
    }
}

extern "C" void kernel_launch(void* const* d_in, const int* in_sizes, int n_in,
                              void* d_out, int out_size, void* d_ws, size_t ws_size,
                              hipStream_t stream) {
  const float* x1 = (const float*)d_in[0];
  const float* x2 = (const float*)d_in[1];
  const float* qw = (const float*)d_in[2];
  const float* qb = (const float*)d_in[3];
  float* out = (float*)d_out;

  u16* ws   = (u16*)d_ws;
  u16* x1b  = ws;                       // 4194304
  u16* x2b  = ws + 4194304;             // 4194304
  u16* wb   = ws + 8388608;             // 3145728
  u16* Qbf  = ws + 11534336;            // 4194304  [B,H,N,HD] (pre-scaled)
  u16* Kbf  = ws + 15728640;            // 4194304  [B,H,N,HD]
  u16* Vtb  = ws + 19922944;            // 4194304  [B,H,HD,N]
  if (ws_size < (size_t)24117248 * 2) return;

  convert_kernel<<<dim3(1024), dim3(256), 0, stream>>>(
      (const fl4*)x1, (const fl4*)x2, (const fl4*)qw,
      (us4*)x1b, (us4*)x2b, (us4*)wb);

  qkv_gemm<<<dim3(768), dim3(256), 0, stream>>>(
      x1b, x2b, wb, qb, Qbf, Kbf, Vtb);

  attn_kernel<<<dim3(16, 32), dim3(256), 0, stream>>>(Qbf, Kbf, Vtb, out);
}

// Round 7
// 182.122 us; speedup vs baseline: 1.0188x; 1.0188x over previous
//
#include <hip/hip_runtime.h>
#include <cstdint>
#include <cstddef>

#define B_   2
#define N_   2048
#define D_   1024
#define H_   16
#define HD_  64
// SCALE * log2(e), folded into Q in the GEMM epilogue
#define QSCALE_ 0.18033688011112042f

typedef unsigned short u16;
typedef unsigned int   u32;
typedef __attribute__((ext_vector_type(8))) short short8;   // bf16 MFMA A/B frag
typedef __attribute__((ext_vector_type(4))) float f32x4;    // MFMA C/D frag (16x16)
typedef __attribute__((ext_vector_type(16))) float f32x16;  // MFMA C/D frag (32x32)
typedef __attribute__((ext_vector_type(4))) float fl4;
typedef __attribute__((ext_vector_type(4))) unsigned short us4;
typedef __attribute__((ext_vector_type(4))) unsigned int u32x4;

#if __has_builtin(__builtin_amdgcn_exp2f)
#define EXP2F(x) __builtin_amdgcn_exp2f(x)   // raw v_exp_f32, no OCML denorm guards
#else
#define EXP2F(x) exp2f(x)
#endif

__device__ __forceinline__ u16 f2bf(float f) {
  u32 u = __builtin_bit_cast(u32, f);
  u += 0x7fffu + ((u >> 16) & 1u);   // RNE; inputs finite
  return (u16)(u >> 16);
}

// pack two f32 -> one u32 of 2 bf16 (RNE), elem0 in low half
__device__ __forceinline__ u32 cvtpk(float lo, float hi) {
  u32 r;
  asm("v_cvt_pk_bf16_f32 %0, %1, %2" : "=v"(r) : "v"(lo), "v"(hi));
  return r;
}

// v_permlane32_swap_b32 a, b: a[32:63] <-> b[0:31]
__device__ __forceinline__ void plswap(u32& a, u32& b) {
  asm volatile("v_permlane32_swap_b32 %0, %1" : "+v"(a), "+v"(b));
}

__device__ __forceinline__ void gload16(const void* g, void* l) {
  typedef __attribute__((address_space(1))) unsigned int gu32;
  typedef __attribute__((address_space(3))) unsigned int lu32;
  __builtin_amdgcn_global_load_lds((gu32*)g, (lu32*)l, 16, 0, 0);
}

// ---------------- fp32 -> bf16 conversion of x1, x2, W ----------------
// Convert-once matters beyond FLOPs: bf16 panels keep the qkv staging working
// set L2-resident (R4 evidence: f32 direct reads -> FETCH 69->191MB, 1.75x slower).
__global__ void convert_kernel(const fl4* __restrict__ x1, const fl4* __restrict__ x2,
                               const fl4* __restrict__ w,
                               us4* __restrict__ o1, us4* __restrict__ o2,
                               us4* __restrict__ ow) {
  const int NX = (B_ * N_ * D_) / 4;   // 1048576
  const int NW = (3 * D_ * D_) / 4;    // 786432
  int stride = gridDim.x * blockDim.x;
  for (int i = blockIdx.x * blockDim.x + threadIdx.x; i < NX; i += stride) {
    fl4 a = x1[i];
    us4 r; r.x = f2bf(a.x); r.y = f2bf(a.y); r.z = f2bf(a.z); r.w = f2bf(a.w);
    o1[i] = r;
    fl4 b = x2[i];
    us4 s; s.x = f2bf(b.x); s.y = f2bf(b.y); s.z = f2bf(b.z); s.w = f2bf(b.w);
    o2[i] = s;
    if (i < NW) {
      fl4 c = w[i];
      us4 t; t.x = f2bf(c.x); t.y = f2bf(c.y); t.z = f2bf(c.z); t.w = f2bf(c.w);
      ow[i] = t;
    }
  }
}

// ---------------- fused QKV GEMM v5: R2's proven 2-barrier structure + T1 XCD swizzle --------
// R6 post-mortem: counted-vmcnt ring = m196's "coarse split without fine interleave" quadrant
// (-25%); sync-structure knob at this tile is null-to-negative (R2 49 / R5 49.7 / R6 62).
// v5 reverts to the byte-exact best-measured loop (48.9us) and keeps ONLY R6's proven-good
// piece: the z-clustered XCD swizzle (FETCH 68.7->56.6MB) — each XCD streams one input tensor
// and keeps its 3 W-panels L2-resident, cutting the load latency paid at each barrier drain.
// z=0: Q from x1 -> [B,H,N,HD] (pre-scaled by SCALE*log2e); z=1: K from x2; z=2: V -> Vt.
__global__ __launch_bounds__(256) void qkv_gemm(
    const u16* __restrict__ x1b, const u16* __restrict__ x2b,
    const u16* __restrict__ wb, const float* __restrict__ bias,
    u16* __restrict__ Qb, u16* __restrict__ Kb, u16* __restrict__ Vtb) {
  const int wg  = blockIdx.x;
  const int swz = (wg & 7) * 96 + (wg >> 3);   // 768%8==0 -> bijective XCD chunks
  const int z   = swz >> 8;                    // 0..2
  const int e0  = ((swz >> 5) & 7) * 128;      // 0..7  *128
  const int m0  = (swz & 31) * 128;            // 0..31 *128

  const u16* X = (z == 0) ? x1b : x2b;
  const u16* W = wb + (size_t)z * D_ * D_;
  const float* bz = bias + z * D_;
  const int tid = threadIdx.x;
  const int lane = tid & 63;
  const int w = tid >> 6;
  const int wr = w >> 1, wc = w & 1;
  const int col = lane & 15, quad = lane >> 4;

  __shared__ __align__(16) u16 As[128 * 32];
  __shared__ __align__(16) u16 Bs[128 * 32];

  f32x4 acc[4][4] = {};

  int off0 = w * 2048 + lane * 16;
  int row0 = off0 >> 6;
  int ke0  = (off0 & 63) >> 1;
  int off1 = off0 + 1024;
  int row1 = off1 >> 6;
  int ke1  = (off1 & 63) >> 1;

  const u16* gA0 = X + (size_t)(m0 + row0) * D_ + ke0;
  const u16* gA1 = X + (size_t)(m0 + row1) * D_ + ke1;
  const u16* gB0 = W + (size_t)(e0 + row0) * D_ + ke0;
  const u16* gB1 = W + (size_t)(e0 + row1) * D_ + ke1;
  u16* lA0 = &As[w * 1024];
  u16* lA1 = &As[w * 1024 + 512];
  u16* lB0 = &Bs[w * 1024];
  u16* lB1 = &Bs[w * 1024 + 512];

  for (int k0 = 0; k0 < D_; k0 += 32) {
    __syncthreads();
    gload16(gA0 + k0, lA0);
    gload16(gA1 + k0, lA1);
    gload16(gB0 + k0, lB0);
    gload16(gB1 + k0, lB1);
    __syncthreads();

    short8 a[4], b[4];
#pragma unroll
    for (int i = 0; i < 4; ++i)
      a[i] = *(const short8*)&As[(wr * 64 + i * 16 + col) * 32 + quad * 8];
#pragma unroll
    for (int j = 0; j < 4; ++j)
      b[j] = *(const short8*)&Bs[(wc * 64 + j * 16 + col) * 32 + quad * 8];
#pragma unroll
    for (int i = 0; i < 4; ++i)
#pragma unroll
      for (int j = 0; j < 4; ++j)
        acc[i][j] = __builtin_amdgcn_mfma_f32_16x16x32_bf16(a[i], b[j], acc[i][j], 0, 0, 0);
  }

#pragma unroll
  for (int j = 0; j < 4; ++j) {
    int eg = e0 + wc * 64 + j * 16 + col;
    float bj = bz[eg];
    int h = eg >> 6, d = eg & 63;
#pragma unroll
    for (int i = 0; i < 4; ++i) {
#pragma unroll
      for (int r = 0; r < 4; ++r) {
        int m = m0 + wr * 64 + i * 16 + quad * 4 + r;
        int bb = m >> 11, n = m & (N_ - 1);
        float v = acc[i][j][r] + bj;
        if (z == 0) v *= QSCALE_;
        u16 o = f2bf(v);
        if (z == 0)      Qb [(((size_t)bb * H_ + h) * N_ + n) * HD_ + d] = o;
        else if (z == 1) Kb [(((size_t)bb * H_ + h) * N_ + n) * HD_ + d] = o;
        else             Vtb[(((size_t)bb * H_ + h) * HD_ + d) * N_ + n] = o;
      }
    }
  }
}

// ---------------- fused attention v6: v5 structure + T1 XCD swizzle (heads clustered) --------
// Grid flattened to 512 and swizzled so each XCD owns 4 complete heads: per-XCD working set
// = 4 x (Q 256K + K 256K + V 256K) = 3MB < 4MB L2 -> the whole attention runs out of L2,
// cutting the K/V load latency paid at the per-tile barrier.  Kernel body unchanged from v5.
__global__ __launch_bounds__(256, 2) void attn_kernel(
    const u16* __restrict__ Qb, const u16* __restrict__ Kb,
    const u16* __restrict__ Vtb, float* __restrict__ out) {
  const int wg  = blockIdx.x;
  const int swz = (wg & 7) * 64 + (wg >> 3);   // 512%8==0 -> bijective XCD chunks
  const int bh  = swz >> 4;                    // 4 heads per XCD chunk
  const int q0  = (swz & 15) * 128;
  const int bb = bh >> 4, h = bh & 15;
  const int tid = threadIdx.x;
  const int lane = tid & 63;
  const int w = tid >> 6;
  const int l31 = lane & 31, hf = lane >> 5, r7 = lane & 7;

  const u16* __restrict__ Q  = Qb  + ((size_t)bh << 17);   // bh * N*HD
  const u16* __restrict__ K  = Kb  + ((size_t)bh << 17);
  const u16* __restrict__ Vt = Vtb + ((size_t)bh << 17);

  __shared__ __align__(16) u16 Ks[2][64 * 64];   // [buf][key][d]  swizzled
  __shared__ __align__(16) u16 Vs[2][64 * 64];   // [buf][d][key]  swizzled
  __shared__ float Ls[4][32];                    // per-wave 1/denominator

  // Q B-frags: col = q = l31, chunk c covers d = c*16 + hf*8 + j
  const u16* Qr = Q + (size_t)(q0 + w * 32 + l31) * HD_;
  short8 qf[4];
#pragma unroll
  for (int c = 0; c < 4; ++c)
    qf[c] = *(const short8*)&Qr[c * 16 + hf * 8];

  // cooperative staging: 256 threads x 16B granules; swizzled write slots
  const int srow = tid >> 3;              // 0..31
  const int sg   = tid & 7;
  const int lw0 = srow * 64 + ((sg ^ (srow & 7)) * 8);
  const int lw1 = lw0 + 2048;                            // row+32: (row&7) unchanged
  const u16* gK = K + tid * 8;                           // + k0*64 (+2048 rows 32..63)
  const u16* gV = Vt + srow * N_ + sg * 8;               // + k0   (+32*N_ d 32..63)

  f32x16 accO[2] = {};
  float lsum = 0.f;

  // prologue: tile 0 -> regs -> buf 0
  short8 kA = *(const short8*)(gK);
  short8 kB = *(const short8*)(gK + 2048);
  short8 vA = *(const short8*)(gV);
  short8 vB = *(const short8*)(gV + 32 * N_);
  *(short8*)&Ks[0][lw0] = kA;
  *(short8*)&Ks[0][lw1] = kB;
  *(short8*)&Vs[0][lw0] = vA;
  *(short8*)&Vs[0][lw1] = vB;

  for (int t = 0; t < N_ / 64; ++t) {
    __syncthreads();                     // buf[cur] writes visible to all waves
    const int cur = t & 1;
    if (t < N_ / 64 - 1) {               // prefetch next tile; consumed only by tail write
      const int k0n = (t + 1) * 64;
      kA = *(const short8*)(gK + k0n * 64);
      kB = *(const short8*)(gK + k0n * 64 + 2048);
      vA = *(const short8*)(gV + k0n);
      vB = *(const short8*)(gV + k0n + 32 * N_);
    }
    const u16* Kc = Ks[cur];
    const u16* Vc = Vs[cur];

    // S^T = K Q^T: A = K[key][d] (row=key=l31 per 32-block), B = Q (col=q)
    f32x16 sT[2] = {};
    __builtin_amdgcn_s_setprio(1);
#pragma unroll
    for (int kb = 0; kb < 2; ++kb) {
      const int rb = (kb * 32 + l31) * 64;
#pragma unroll
      for (int c = 0; c < 4; ++c) {
        short8 kf = *(const short8*)&Kc[rb + (((c * 2 + hf) ^ r7) * 8)];
        sT[kb] = __builtin_amdgcn_mfma_f32_32x32x16_bf16(kf, qf[c], sT[kb], 0, 0, 0);
      }
    }
    __builtin_amdgcn_s_setprio(0);

    // exp2 in-register (arg pre-scaled by SCALE*log2e; no max needed), scalar denom
#pragma unroll
    for (int kb = 0; kb < 2; ++kb)
#pragma unroll
      for (int i = 0; i < 16; ++i) {
        float e = EXP2F(sT[kb][i]);
        lsum += e;
        sT[kb][i] = e;
      }

    // build PV A-frags fully in-register: chunk kc = keys kc*16..+15 of the tile.
    short8 pf[4];
#pragma unroll
    for (int kc = 0; kc < 4; ++kc) {
      const int kb = kc >> 1, o = (kc & 1) * 8;
      u32 X = cvtpk(sT[kb][o + 0], sT[kb][o + 1]);
      u32 Y = cvtpk(sT[kb][o + 4], sT[kb][o + 5]);
      plswap(X, Y);
      u32 Z = cvtpk(sT[kb][o + 2], sT[kb][o + 3]);
      u32 W = cvtpk(sT[kb][o + 6], sT[kb][o + 7]);
      plswap(Z, W);
      u32x4 pw = {X, Z, Y, W};
      pf[kc] = __builtin_bit_cast(short8, pw);
    }

    // O += P V : A = P (row=q), B = V^T[d][key] (col=d), k=key
    __builtin_amdgcn_s_setprio(1);
#pragma unroll
    for (int db = 0; db < 2; ++db) {
      const int rb = (db * 32 + l31) * 64;
#pragma unroll
      for (int kc = 0; kc < 4; ++kc) {
        short8 vf = *(const short8*)&Vc[rb + (((kc * 2 + hf) ^ r7) * 8)];
        accO[db] = __builtin_amdgcn_mfma_f32_32x32x16_bf16(pf[kc], vf, accO[db], 0, 0, 0);
      }
    }
    __builtin_amdgcn_s_setprio(0);

    // tail: commit prefetched tile into the other buffer (vmcnt lands here, hidden)
    if (t < N_ / 64 - 1) {
      u16* Kn = (u16*)Ks[cur ^ 1];
      u16* Vn = (u16*)Vs[cur ^ 1];
      *(short8*)&Kn[lw0] = kA;
      *(short8*)&Kn[lw1] = kB;
      *(short8*)&Vn[lw0] = vA;
      *(short8*)&Vn[lw1] = vB;
    }
  }

  // denominator: lane pair (l, l^32) holds complementary key halves for q = l31
  lsum += __shfl_xor(lsum, 32);
  if (hf == 0) Ls[w][l31] = 1.0f / lsum;
  __syncthreads();

  float rinv[16];
#pragma unroll
  for (int r = 0; r < 16; ++r)
    rinv[r] = Ls[w][(r & 3) + 8 * (r >> 2) + 4 * hf];

#pragma unroll
  for (int db = 0; db < 2; ++db)
#pragma unroll
    for (int r = 0; r < 16; ++r) {
      int n = q0 + w * 32 + (r & 3) + 8 * (r >> 2) + 4 * hf;
      int e = h * HD_ + db * 32 + l31;
      out[((size_t)bb * N_ + n) * D_ + e] = accO[db][r] * rinv[r];
    }
}

extern "C" void kernel_launch(void* const* d_in, const int* in_sizes, int n_in,
                              void* d_out, int out_size, void* d_ws, size_t ws_size,
                              hipStream_t stream) {
  const float* x1 = (const float*)d_in[0];
  const float* x2 = (const float*)d_in[1];
  const float* qw = (const float*)d_in[2];
  const float* qb = (const float*)d_in[3];
  float* out = (float*)d_out;

  u16* ws   = (u16*)d_ws;
  u16* x1b  = ws;                       // 4194304
  u16* x2b  = ws + 4194304;             // 4194304
  u16* wb   = ws + 8388608;             // 3145728
  u16* Qbf  = ws + 11534336;            // 4194304  [B,H,N,HD] (pre-scaled)
  u16* Kbf  = ws + 15728640;            // 4194304  [B,H,N,HD]
  u16* Vtb  = ws + 19922944;            // 4194304  [B,H,HD,N]
  if (ws_size < (size_t)24117248 * 2) return;

  convert_kernel<<<dim3(1024), dim3(256), 0, stream>>>(
      (const fl4*)x1, (const fl4*)x2, (const fl4*)qw,
      (us4*)x1b, (us4*)x2b, (us4*)wb);

  qkv_gemm<<<dim3(768), dim3(256), 0, stream>>>(
      x1b, x2b, wb, qb, Qbf, Kbf, Vtb);

  attn_kernel<<<dim3(512), dim3(256), 0, stream>>>(Qbf, Kbf, Vtb, out);
}

// Round 8
// 171.441 us; speedup vs baseline: 1.0822x; 1.0623x over previous
//
#include <hip/hip_runtime.h>
#include <cstdint>
#include <cstddef>

#define B_   2
#define N_   2048
#define D_   1024
#define H_   16
#define HD_  64
// SCALE * log2(e), folded into Q in the GEMM epilogue
#define QSCALE_ 0.18033688011112042f

typedef unsigned short u16;
typedef unsigned int   u32;
typedef __attribute__((ext_vector_type(8))) short short8;   // bf16 MFMA A/B frag
typedef __attribute__((ext_vector_type(4))) float f32x4;    // MFMA C/D frag (16x16)
typedef __attribute__((ext_vector_type(16))) float f32x16;  // MFMA C/D frag (32x32)
typedef __attribute__((ext_vector_type(4))) float fl4;
typedef __attribute__((ext_vector_type(4))) unsigned short us4;
typedef __attribute__((ext_vector_type(4))) unsigned int u32x4;

#if __has_builtin(__builtin_amdgcn_exp2f)
#define EXP2F(x) __builtin_amdgcn_exp2f(x)   // raw v_exp_f32, no OCML denorm guards
#else
#define EXP2F(x) exp2f(x)
#endif

__device__ __forceinline__ u16 f2bf(float f) {
  u32 u = __builtin_bit_cast(u32, f);
  u += 0x7fffu + ((u >> 16) & 1u);   // RNE; inputs finite
  return (u16)(u >> 16);
}

// pack two f32 -> one u32 of 2 bf16 (RNE), elem0 in low half
__device__ __forceinline__ u32 cvtpk(float lo, float hi) {
  u32 r;
  asm("v_cvt_pk_bf16_f32 %0, %1, %2" : "=v"(r) : "v"(lo), "v"(hi));
  return r;
}

// v_permlane32_swap_b32 a, b: a[32:63] <-> b[0:31]
__device__ __forceinline__ void plswap(u32& a, u32& b) {
  asm volatile("v_permlane32_swap_b32 %0, %1" : "+v"(a), "+v"(b));
}

__device__ __forceinline__ void gload16(const void* g, void* l) {
  typedef __attribute__((address_space(1))) unsigned int gu32;
  typedef __attribute__((address_space(3))) unsigned int lu32;
  __builtin_amdgcn_global_load_lds((gu32*)g, (lu32*)l, 16, 0, 0);
}

// ---------------- fp32 -> bf16 conversion of x1, x2, W ----------------
// Convert-once matters beyond FLOPs: bf16 panels keep the qkv staging working
// set L2-resident (R4 evidence: f32 direct reads -> FETCH 69->191MB, 1.75x slower).
__global__ void convert_kernel(const fl4* __restrict__ x1, const fl4* __restrict__ x2,
                               const fl4* __restrict__ w,
                               us4* __restrict__ o1, us4* __restrict__ o2,
                               us4* __restrict__ ow) {
  const int NX = (B_ * N_ * D_) / 4;   // 1048576
  const int NW = (3 * D_ * D_) / 4;    // 786432
  int stride = gridDim.x * blockDim.x;
  for (int i = blockIdx.x * blockDim.x + threadIdx.x; i < NX; i += stride) {
    fl4 a = x1[i];
    us4 r; r.x = f2bf(a.x); r.y = f2bf(a.y); r.z = f2bf(a.z); r.w = f2bf(a.w);
    o1[i] = r;
    fl4 b = x2[i];
    us4 s; s.x = f2bf(b.x); s.y = f2bf(b.y); s.z = f2bf(b.z); s.w = f2bf(b.w);
    o2[i] = s;
    if (i < NW) {
      fl4 c = w[i];
      us4 t; t.x = f2bf(c.x); t.y = f2bf(c.y); t.z = f2bf(c.z); t.w = f2bf(c.w);
      ow[i] = t;
    }
  }
}

// ---------------- fused QKV GEMM v6: R2 2-barrier structure + BK=64 + XOR-swizzled LDS --------
// R7 post-mortem: qkv is latency/sync-bound, not traffic-bound (z-XCD swizzle cut FETCH 40%
// but cost +16% time).  v6 reverts to the dim3(8,32,3) champion grid and attacks drain
// FREQUENCY: BK 32->64 halves barrier-pair count (32->16) and doubles per-drain compute
// (16->32 MFMA).  LDS 32KB, occupancy still grid-capped (3 blocks/CU).  The 128B row also
// enables a conflict-free XOR swizzle (rule #21 form): LINEAR gload_lds dest + inverse-
// swizzled global SOURCE (granule (l&7)^(l>>3), same 128B segment -> coalescing kept) +
// swizzled READ offsets ((quad^(col&7))*8, frag1 = ^32).  8 lanes per 4-bank group = optimal.
// z=0: Q from x1 -> [B,H,N,HD] (pre-scaled by SCALE*log2e); z=1: K from x2; z=2: V -> Vt.
__global__ __launch_bounds__(256) void qkv_gemm(
    const u16* __restrict__ x1b, const u16* __restrict__ x2b,
    const u16* __restrict__ wb, const float* __restrict__ bias,
    u16* __restrict__ Qb, u16* __restrict__ Kb, u16* __restrict__ Vtb) {
  const int z = blockIdx.z;
  const u16* X = (z == 0) ? x1b : x2b;
  const u16* W = wb + (size_t)z * D_ * D_;
  const float* bz = bias + z * D_;
  const int m0 = blockIdx.y * 128;
  const int e0 = blockIdx.x * 128;
  const int tid = threadIdx.x;
  const int lane = tid & 63;
  const int w = tid >> 6;
  const int wr = w >> 1, wc = w & 1;
  const int col = lane & 15, quad = lane >> 4;

  __shared__ __align__(16) u16 As[128 * 64];   // [row][64], granule-swizzled
  __shared__ __align__(16) u16 Bs[128 * 64];

  f32x4 acc[4][4] = {};

  // staging: round rr covers rows rr*32 + w*8 + (l>>3); dest granule rr*256+w*64+l (linear).
  // phys slot s=l&7 at row R (R&7 == l>>3) must hold logical granule s^(R&7) -> source
  // granule cg = (l&7)^(l>>3).
  const int cg = (lane & 7) ^ (lane >> 3);
  const u16* sA = X + (size_t)(m0 + w * 8 + (lane >> 3)) * D_ + cg * 8;
  const u16* sB = W + (size_t)(e0 + w * 8 + (lane >> 3)) * D_ + cg * 8;
  u16* dA = &As[w * 512];                      // wave-uniform; HW adds lane*16B
  u16* dB = &Bs[w * 512];

  // swizzled read offset: logical granule quad at row (..+col) -> phys (quad^(col&7))
  const int pg = (quad ^ (col & 7)) * 8;       // frag k=0..31; frag k=32..63 at pg^32

  for (int k0 = 0; k0 < D_; k0 += 64) {
    __syncthreads();                           // write-after-read: all waves done with tile
#pragma unroll
    for (int rr = 0; rr < 4; ++rr) {
      gload16(sA + (size_t)rr * 32 * D_ + k0, dA + rr * 2048);
      gload16(sB + (size_t)rr * 32 * D_ + k0, dB + rr * 2048);
    }
    __syncthreads();                           // drain: tile resident

    short8 a[4][2], b[4][2];
#pragma unroll
    for (int i = 0; i < 4; ++i) {
      const int rb = (wr * 64 + i * 16 + col) * 64;
      a[i][0] = *(const short8*)&As[rb + pg];
      a[i][1] = *(const short8*)&As[rb + (pg ^ 32)];
    }
#pragma unroll
    for (int j = 0; j < 4; ++j) {
      const int rb = (wc * 64 + j * 16 + col) * 64;
      b[j][0] = *(const short8*)&Bs[rb + pg];
      b[j][1] = *(const short8*)&Bs[rb + (pg ^ 32)];
    }
    __builtin_amdgcn_s_setprio(1);
#pragma unroll
    for (int i = 0; i < 4; ++i)
#pragma unroll
      for (int j = 0; j < 4; ++j) {
        acc[i][j] = __builtin_amdgcn_mfma_f32_16x16x32_bf16(a[i][0], b[j][0], acc[i][j], 0, 0, 0);
        acc[i][j] = __builtin_amdgcn_mfma_f32_16x16x32_bf16(a[i][1], b[j][1], acc[i][j], 0, 0, 0);
      }
    __builtin_amdgcn_s_setprio(0);
  }

#pragma unroll
  for (int j = 0; j < 4; ++j) {
    int eg = e0 + wc * 64 + j * 16 + col;
    float bj = bz[eg];
    int h = eg >> 6, d = eg & 63;
#pragma unroll
    for (int i = 0; i < 4; ++i) {
#pragma unroll
      for (int r = 0; r < 4; ++r) {
        int m = m0 + wr * 64 + i * 16 + quad * 4 + r;
        int bb = m >> 11, n = m & (N_ - 1);
        float v = acc[i][j][r] + bj;
        if (z == 0) v *= QSCALE_;
        u16 o = f2bf(v);
        if (z == 0)      Qb [(((size_t)bb * H_ + h) * N_ + n) * HD_ + d] = o;
        else if (z == 1) Kb [(((size_t)bb * H_ + h) * N_ + n) * HD_ + d] = o;
        else             Vtb[(((size_t)bb * H_ + h) * HD_ + d) * N_ + n] = o;
      }
    }
  }
}

// ---------------- fused attention v5: 32x32 MFMA, swapped QK^T, in-register softmax ----------------
// block = 4 waves x 32 q-rows = 128 q; BK = 64 keys/tile; grid 16 x 32 = 512 (2 blocks/CU).
// S^T = mfma(K, Q): col=lane&31 = q (ONE q per lane), row = key = (reg&3)+8*(reg>>2)+4*(lane>>5).
// Softmax denominator is a per-lane scalar (+1 shfl at epilogue). P -> PV A-frags built fully
// in-register: cvt_pk_bf16 pairs + permlane32_swap (T12).  No P LDS, no lgkm serialization.
// K/V tiles: double-buffered XOR-swizzled [64][64], one barrier/tile, reg-staged prefetch.
// (R2-exact: measured champion; R7's head-clustered XCD swizzle was neutral -> reverted.)
__global__ __launch_bounds__(256, 2) void attn_kernel(
    const u16* __restrict__ Qb, const u16* __restrict__ Kb,
    const u16* __restrict__ Vtb, float* __restrict__ out) {
  const int bh = blockIdx.y;                 // 0..31
  const int bb = bh >> 4, h = bh & 15;
  const int q0 = blockIdx.x * 128;
  const int tid = threadIdx.x;
  const int lane = tid & 63;
  const int w = tid >> 6;
  const int l31 = lane & 31, hf = lane >> 5, r7 = lane & 7;

  const u16* __restrict__ Q  = Qb  + ((size_t)bh << 17);   // bh * N*HD
  const u16* __restrict__ K  = Kb  + ((size_t)bh << 17);
  const u16* __restrict__ Vt = Vtb + ((size_t)bh << 17);

  __shared__ __align__(16) u16 Ks[2][64 * 64];   // [buf][key][d]  swizzled
  __shared__ __align__(16) u16 Vs[2][64 * 64];   // [buf][d][key]  swizzled
  __shared__ float Ls[4][32];                    // per-wave 1/denominator

  // Q B-frags: col = q = l31, chunk c covers d = c*16 + hf*8 + j
  const u16* Qr = Q + (size_t)(q0 + w * 32 + l31) * HD_;
  short8 qf[4];
#pragma unroll
  for (int c = 0; c < 4; ++c)
    qf[c] = *(const short8*)&Qr[c * 16 + hf * 8];

  // cooperative staging: 256 threads x 16B granules; swizzled write slots
  const int srow = tid >> 3;              // 0..31
  const int sg   = tid & 7;
  const int lw0 = srow * 64 + ((sg ^ (srow & 7)) * 8);
  const int lw1 = lw0 + 2048;                            // row+32: (row&7) unchanged
  const u16* gK = K + tid * 8;                           // + k0*64 (+2048 rows 32..63)
  const u16* gV = Vt + srow * N_ + sg * 8;               // + k0   (+32*N_ d 32..63)

  f32x16 accO[2] = {};
  float lsum = 0.f;

  // prologue: tile 0 -> regs -> buf 0
  short8 kA = *(const short8*)(gK);
  short8 kB = *(const short8*)(gK + 2048);
  short8 vA = *(const short8*)(gV);
  short8 vB = *(const short8*)(gV + 32 * N_);
  *(short8*)&Ks[0][lw0] = kA;
  *(short8*)&Ks[0][lw1] = kB;
  *(short8*)&Vs[0][lw0] = vA;
  *(short8*)&Vs[0][lw1] = vB;

  for (int t = 0; t < N_ / 64; ++t) {
    __syncthreads();                     // buf[cur] writes visible to all waves
    const int cur = t & 1;
    if (t < N_ / 64 - 1) {               // prefetch next tile; consumed only by tail write
      const int k0n = (t + 1) * 64;
      kA = *(const short8*)(gK + k0n * 64);
      kB = *(const short8*)(gK + k0n * 64 + 2048);
      vA = *(const short8*)(gV + k0n);
      vB = *(const short8*)(gV + k0n + 32 * N_);
    }
    const u16* Kc = Ks[cur];
    const u16* Vc = Vs[cur];

    // S^T = K Q^T: A = K[key][d] (row=key=l31 per 32-block), B = Q (col=q)
    f32x16 sT[2] = {};
    __builtin_amdgcn_s_setprio(1);
#pragma unroll
    for (int kb = 0; kb < 2; ++kb) {
      const int rb = (kb * 32 + l31) * 64;
#pragma unroll
      for (int c = 0; c < 4; ++c) {
        short8 kf = *(const short8*)&Kc[rb + (((c * 2 + hf) ^ r7) * 8)];
        sT[kb] = __builtin_amdgcn_mfma_f32_32x32x16_bf16(kf, qf[c], sT[kb], 0, 0, 0);
      }
    }
    __builtin_amdgcn_s_setprio(0);

    // exp2 in-register (arg pre-scaled by SCALE*log2e; no max needed), scalar denom
#pragma unroll
    for (int kb = 0; kb < 2; ++kb)
#pragma unroll
      for (int i = 0; i < 16; ++i) {
        float e = EXP2F(sT[kb][i]);
        lsum += e;
        sT[kb][i] = e;
      }

    // build PV A-frags fully in-register: chunk kc = keys kc*16..+15 of the tile.
    short8 pf[4];
#pragma unroll
    for (int kc = 0; kc < 4; ++kc) {
      const int kb = kc >> 1, o = (kc & 1) * 8;
      u32 X = cvtpk(sT[kb][o + 0], sT[kb][o + 1]);
      u32 Y = cvtpk(sT[kb][o + 4], sT[kb][o + 5]);
      plswap(X, Y);
      u32 Z = cvtpk(sT[kb][o + 2], sT[kb][o + 3]);
      u32 W = cvtpk(sT[kb][o + 6], sT[kb][o + 7]);
      plswap(Z, W);
      u32x4 pw = {X, Z, Y, W};
      pf[kc] = __builtin_bit_cast(short8, pw);
    }

    // O += P V : A = P (row=q), B = V^T[d][key] (col=d), k=key
    __builtin_amdgcn_s_setprio(1);
#pragma unroll
    for (int db = 0; db < 2; ++db) {
      const int rb = (db * 32 + l31) * 64;
#pragma unroll
      for (int kc = 0; kc < 4; ++kc) {
        short8 vf = *(const short8*)&Vc[rb + (((kc * 2 + hf) ^ r7) * 8)];
        accO[db] = __builtin_amdgcn_mfma_f32_32x32x16_bf16(pf[kc], vf, accO[db], 0, 0, 0);
      }
    }
    __builtin_amdgcn_s_setprio(0);

    // tail: commit prefetched tile into the other buffer (vmcnt lands here, hidden)
    if (t < N_ / 64 - 1) {
      u16* Kn = (u16*)Ks[cur ^ 1];
      u16* Vn = (u16*)Vs[cur ^ 1];
      *(short8*)&Kn[lw0] = kA;
      *(short8*)&Kn[lw1] = kB;
      *(short8*)&Vn[lw0] = vA;
      *(short8*)&Vn[lw1] = vB;
    }
  }

  // denominator: lane pair (l, l^32) holds complementary key halves for q = l31
  lsum += __shfl_xor(lsum, 32);
  if (hf == 0) Ls[w][l31] = 1.0f / lsum;
  __syncthreads();

  float rinv[16];
#pragma unroll
  for (int r = 0; r < 16; ++r)
    rinv[r] = Ls[w][(r & 3) + 8 * (r >> 2) + 4 * hf];

#pragma unroll
  for (int db = 0; db < 2; ++db)
#pragma unroll
    for (int r = 0; r < 16; ++r) {
      int n = q0 + w * 32 + (r & 3) + 8 * (r >> 2) + 4 * hf;
      int e = h * HD_ + db * 32 + l31;
      out[((size_t)bb * N_ + n) * D_ + e] = accO[db][r] * rinv[r];
    }
}

extern "C" void kernel_launch(void* const* d_in, const int* in_sizes, int n_in,
                              void* d_out, int out_size, void* d_ws, size_t ws_size,
                              hipStream_t stream) {
  const float* x1 = (const float*)d_in[0];
  const float* x2 = (const float*)d_in[1];
  const float* qw = (const float*)d_in[2];
  const float* qb = (const float*)d_in[3];
  float* out = (float*)d_out;

  u16* ws   = (u16*)d_ws;
  u16* x1b  = ws;                       // 4194304
  u16* x2b  = ws + 4194304;             // 4194304
  u16* wb   = ws + 8388608;             // 3145728
  u16* Qbf  = ws + 11534336;            // 4194304  [B,H,N,HD] (pre-scaled)
  u16* Kbf  = ws + 15728640;            // 4194304  [B,H,N,HD]
  u16* Vtb  = ws + 19922944;            // 4194304  [B,H,HD,N]
  if (ws_size < (size_t)24117248 * 2) return;

  convert_kernel<<<dim3(1024), dim3(256), 0, stream>>>(
      (const fl4*)x1, (const fl4*)x2, (const fl4*)qw,
      (us4*)x1b, (us4*)x2b, (us4*)wb);

  qkv_gemm<<<dim3(8, 32, 3), dim3(256), 0, stream>>>(
      x1b, x2b, wb, qb, Qbf, Kbf, Vtb);

  attn_kernel<<<dim3(16, 32), dim3(256), 0, stream>>>(Qbf, Kbf, Vtb, out);
}